// Round 2
// baseline (539.355 us; speedup 1.0000x reference)
//
#include <hip/hip_runtime.h>
#include <math.h>

#define Bn 128
#define Tn 1024
#define Nn 128
#define NEGV -10000.0f

// ws layout:
//   [0, 8192)        lsePart  float [128][16]
//   [8192, 8704)     rawScore float [128]
//   [8704, 9216)     bestTag  int   [128]
//   [16384, +16MB)   bp       u8    [128][1024][128]
#define WS_BP_OFF 16384
#define WS_BP_BYTES ((size_t)Bn * Tn * Nn)

// ---------------- kernel A: lse partial sums -------------------------------
// grid = 128 b * 16 chunks, block = 256 (4 waves). Each block: 64 t's.
__global__ __launch_bounds__(256) void lse_kernel(
    const float* __restrict__ u, const int* __restrict__ lengths,
    float* __restrict__ lsePart)
{
    int b  = blockIdx.x >> 4;
    int ch = blockIdx.x & 15;
    int lane = threadIdx.x & 63, wv = threadIdx.x >> 6;
    int lb = lengths[b];
    float acc = 0.0f;
    for (int it = 0; it < 16; ++it) {
        int t = ch * 64 + it * 4 + wv;
        const float* row = u + ((size_t)b * Tn + t) * Nn;
        float2 v = reinterpret_cast<const float2*>(row)[lane];
        float mx = fmaxf(v.x, v.y);
        #pragma unroll
        for (int o = 32; o; o >>= 1) mx = fmaxf(mx, __shfl_xor(mx, o, 64));
        float s = __expf(v.x - mx) + __expf(v.y - mx);
        #pragma unroll
        for (int o = 32; o; o >>= 1) s += __shfl_xor(s, o, 64);
        float lse = mx + __logf(s);
        if (t < lb) acc += lse;
    }
    __shared__ float wacc[4];
    if (lane == 0) wacc[wv] = acc;
    __syncthreads();
    if (threadIdx.x == 0)
        lsePart[b * 16 + ch] = (wacc[0] + wacc[1]) + (wacc[2] + wacc[3]);
}

// ---------------- kernel B: viterbi forward --------------------------------
// pack low-5 mantissa bits with COMPLEMENTED local index (31-jj), so that
// fmaxf on tied (masked-equal) scores picks the SMALLEST j — matching
// jnp.argmax first-occurrence semantics.
__device__ __forceinline__ float packc(float v, int cjj) {
    return __uint_as_float((__float_as_uint(v) & 0xFFFFFFE0u) | (unsigned)cjj);
}

__global__ __launch_bounds__(512) void viterbi_kernel(
    const float* __restrict__ u, const float* __restrict__ trans,
    const int* __restrict__ lengths, unsigned char* __restrict__ bp,
    float* __restrict__ rawScore, int* __restrict__ bestTag, int haveBp)
{
    const int b   = blockIdx.x;
    const int tid = threadIdx.x;
    const int i   = tid & 127;
    const int q   = tid >> 7;          // 0..3, j-range [32q, 32q+32)
    const int lb  = lengths[b];

    __shared__ float alpha[128];
    __shared__ float pval[4][128];
    __shared__ float ubuf[2][16][128];
    __shared__ float redv[2];

    // trans chunk -> regs
    float treg[32];
    {
        const float4* t4 = reinterpret_cast<const float4*>(trans + i * 128 + q * 32);
        #pragma unroll
        for (int g = 0; g < 8; ++g) {
            float4 v = t4[g];
            treg[4*g+0] = v.x; treg[4*g+1] = v.y; treg[4*g+2] = v.z; treg[4*g+3] = v.w;
        }
    }
    float te = 0.0f;
    if (tid < 128) te = trans[2 * 128 + i];   // EOS row

    if (tid < 128) alpha[i] = (i == 1) ? 0.0f : NEGV;   // GO = 1

    const float* ub = u + (size_t)b * Tn * Nn;

    // prologue: chunk0 -> LDS buf0, chunk1 -> regs
    {
        float4 v0 = reinterpret_cast<const float4*>(ub)[tid];
        reinterpret_cast<float4*>(&ubuf[0][0][0])[tid] = v0;
    }
    float4 nxt = reinterpret_cast<const float4*>(ub + 16 * 128)[tid];
    __syncthreads();

    const int nsteps  = lb;                 // 512..1024
    const int nchunks = (nsteps + 15) >> 4;
    for (int tc = 0; tc < nchunks; ++tc) {
        const int cur = tc & 1;
        if (tc + 1 < 64) {
            reinterpret_cast<float4*>(&ubuf[cur ^ 1][0][0])[tid] = nxt;
            if (tc + 2 < 64)
                nxt = reinterpret_cast<const float4*>(ub + (size_t)(tc + 2) * 16 * 128)[tid];
        }
        const int kend = min(16, nsteps - tc * 16);
        for (int k = 0; k < kend; ++k) {
            const int t = tc * 16 + k;
            float m = -INFINITY;
            const float4* a4 = reinterpret_cast<const float4*>(alpha) + q * 8;
            #pragma unroll
            for (int g = 0; g < 8; ++g) {
                float4 av = a4[g];
                float p0 = packc(av.x + treg[4*g+0], 31 - (4*g+0));
                float p1 = packc(av.y + treg[4*g+1], 31 - (4*g+1));
                float p2 = packc(av.z + treg[4*g+2], 31 - (4*g+2));
                float p3 = packc(av.w + treg[4*g+3], 31 - (4*g+3));
                asm("v_max3_f32 %0, %1, %2, %3" : "=v"(m) : "v"(m), "v"(p0), "v"(p1));
                asm("v_max3_f32 %0, %1, %2, %3" : "=v"(m) : "v"(m), "v"(p2), "v"(p3));
            }
            // low-7 bits become 127 - (32q + jj) = ((3-q)<<5) | (31-jj)
            unsigned mb = __float_as_uint(m);
            mb = (mb & 0xFFFFFF80u) | (unsigned)((3 - q) << 5) | (mb & 31u);
            pval[q][i] = __uint_as_float(mb);
            __syncthreads();
            if (tid < 128) {
                float c0 = pval[0][i], c1 = pval[1][i], c2 = pval[2][i], c3 = pval[3][i];
                float mm = fmaxf(fmaxf(c0, c1), fmaxf(c2, c3));
                if (haveBp)
                    bp[((size_t)b * Tn + t) * Nn + i] =
                        (unsigned char)(127u - (__float_as_uint(mm) & 127u));
                alpha[i] = mm + ubuf[cur][k][i];   // t < nsteps guaranteed
            }
            __syncthreads();
        }
    }

    // terminal reduce: argmax_i (alpha[i] + trans[EOS][i]), complement-packed
    if (tid < 128) {
        float c = alpha[i] + te;
        float p = __uint_as_float((__float_as_uint(c) & 0xFFFFFF80u) | (unsigned)(127 - i));
        #pragma unroll
        for (int o = 32; o; o >>= 1) p = fmaxf(p, __shfl_xor(p, o, 64));
        if ((tid & 63) == 0) redv[tid >> 6] = p;
    }
    __syncthreads();
    if (tid == 0) {
        float mfin = fmaxf(redv[0], redv[1]);
        rawScore[b] = mfin;
        bestTag[b]  = (int)(127u - (__float_as_uint(mfin) & 127u));
    }
}

// ---------------- kernel C: backtrace + finalize ---------------------------
__global__ __launch_bounds__(1024) void backtrace_kernel(
    const unsigned char* __restrict__ bp, const int* __restrict__ lengths,
    const int* __restrict__ bestTag, const float* __restrict__ rawScore,
    const float* __restrict__ lsePart, float* __restrict__ outPath,
    float* __restrict__ outScore, int haveBp)
{
    const int b    = blockIdx.x;
    const int tid  = threadIdx.x;
    const int lb   = lengths[b];
    const int btag = bestTag[b];

    if (tid == 0) {
        float o = 0.0f;
        #pragma unroll
        for (int c = 0; c < 16; ++c) o += lsePart[b * 16 + c];
        outScore[b] = rawScore[b] - o;
    }

    if (!haveBp) {            // degraded mode: ws too small for bp
        outPath[b * 1024 + tid] = (float)btag;
        return;
    }

    __shared__ unsigned char stage[256][128];   // 32 KB
    __shared__ unsigned char M[64][128];        // 8 KB  (segment maps, C=16)
    __shared__ unsigned char ebound[65];
    const unsigned char* bpb = bp + (size_t)b * Tn * Nn;

    const int x = tid & 127, sg = tid >> 7;     // sg 0..7
    for (int quarter = 0; quarter < 4; ++quarter) {
        __syncthreads();
        {   // stage bp rows (t+1) in [256q+1, 256q+256]
            const uchar4* src =
                reinterpret_cast<const uchar4*>(bpb + (size_t)(256 * quarter + 1) * 128);
            uchar4* dst = reinterpret_cast<uchar4*>(&stage[0][0]);
            #pragma unroll
            for (int it = 0; it < 8; ++it) dst[tid + it * 1024] = src[tid + it * 1024];
        }
        __syncthreads();
        #pragma unroll
        for (int it = 0; it < 2; ++it) {
            int s = quarter * 16 + sg + it * 8;
            int y = x;
            for (int k = 15; k >= 0; --k) {
                int t = s * 16 + k;
                if (t < lb - 1) y = stage[t - 256 * quarter][y];  // slot=(t+1)-(256q+1)
            }
            M[s][x] = (unsigned char)y;
        }
    }
    __syncthreads();
    if (tid == 0) {
        int e = btag;
        ebound[64] = (unsigned char)e;
        for (int s = 63; s >= 0; --s) { e = M[s][e]; ebound[s] = (unsigned char)e; }
    }
    __syncthreads();
    if (tid < 64) {            // phase 3: one segment per lane
        int s = tid;
        int cur = ebound[s + 1];
        for (int k = 15; k >= 0; --k) {
            int t = s * 16 + k;
            int nx = cur;
            if (t < lb - 1) nx = bpb[(size_t)(t + 1) * 128 + cur];
            outPath[b * 1024 + t] = (float)nx;
            cur = nx;
        }
    }
}

// ---------------------------------------------------------------------------
extern "C" void kernel_launch(void* const* d_in, const int* in_sizes, int n_in,
                              void* d_out, int out_size, void* d_ws, size_t ws_size,
                              hipStream_t stream)
{
    const float* unaries = (const float*)d_in[0];
    const float* trans   = (const float*)d_in[1];
    const int*   lengths = (const int*)d_in[2];

    float* outPath  = (float*)d_out;                 // [128][1024]
    float* outScore = (float*)d_out + Bn * Tn;       // [128]

    char* ws = (char*)d_ws;
    float* lsePart  = (float*)(ws);
    float* rawScore = (float*)(ws + 8192);
    int*   bestTag  = (int*)(ws + 8704);
    unsigned char* bp = (unsigned char*)(ws + WS_BP_OFF);
    int haveBp = (ws_size >= (size_t)WS_BP_OFF + WS_BP_BYTES) ? 1 : 0;

    lse_kernel<<<dim3(Bn * 16), dim3(256), 0, stream>>>(unaries, lengths, lsePart);
    viterbi_kernel<<<dim3(Bn), dim3(512), 0, stream>>>(unaries, trans, lengths, bp,
                                                       rawScore, bestTag, haveBp);
    backtrace_kernel<<<dim3(Bn), dim3(1024), 0, stream>>>(bp, lengths, bestTag, rawScore,
                                                          lsePart, outPath, outScore, haveBp);
}